// Round 1
// baseline (404.610 us; speedup 1.0000x reference)
//
#include <hip/hip_runtime.h>
#include <math.h>

#define OBS_DIM 115
#define N_AGENTS 11
// ID block: cols 97..107 (11 cols)

__global__ __launch_bounds__(256) void qmix_kernel(
    const float* __restrict__ q,    // [B, 11]
    const float* __restrict__ gs,   // [B, 1265]
    float* __restrict__ out,        // [B]
    int B)
{
    int r = blockIdx.x * blockDim.x + threadIdx.x;
    if (r >= B) return;

    const float* row = gs + (long)r * (N_AGENTS * OBS_DIM);

    // ball + team info (all within agent 0's block)
    float bx = row[88];
    float by = row[89];
    float team = row[95];
    float gx0 = bx - 1.0f;
    float ball_goal_dist = sqrtf(gx0 * gx0 + by * by);
    bool valid = (team != 0.0f) && (ball_goal_dist > 0.19f) && (ball_goal_dist < 0.99f);

    float dist[N_AGENTS];
    float gd[N_AGENTS];

    #pragma unroll
    for (int a = 0; a < N_AGENTS; ++a) {
        const float* base = row + a * OBS_DIM;
        // argmax over base[97..107], first-max tie-break (strict >)
        float best = base[97];
        int bi = 0;
        #pragma unroll
        for (int j = 1; j < 11; ++j) {
            float v = base[97 + j];
            if (v > best) { best = v; bi = j; }
        }
        float px = base[2 * bi];
        float py = base[2 * bi + 1];
        float ddx = px - bx;
        float ddy = py - by;
        dist[a] = sqrtf(ddx * ddx + ddy * ddy);
        float ggx = px - 1.0f;
        gd[a] = sqrtf(ggx * ggx + py * py);
    }

    // argmin over dist, first-min tie-break (strict <)
    int holder = 0;
    float dmin = dist[0];
    #pragma unroll
    for (int a = 1; a < N_AGENTS; ++a) {
        if (dist[a] < dmin) { dmin = dist[a]; holder = a; }
    }

    // combined + softmax
    float comb[N_AGENTS];
    float m = -INFINITY;
    #pragma unroll
    for (int a = 0; a < N_AGENTS; ++a) {
        float c;
        if (valid) {
            c = (a == holder) ? 5.0f : 0.0f;
        } else {
            c = 1.0f / (gd[a] + 1e-6f);
        }
        comb[a] = c;
        m = fmaxf(m, c);
    }

    const float* qr = q + (long)r * N_AGENTS;
    float s = 0.0f;
    float acc = 0.0f;
    #pragma unroll
    for (int a = 0; a < N_AGENTS; ++a) {
        float w = expf(comb[a] - m);
        s += w;
        acc += qr[a] * w;
    }

    out[r] = acc * (float)N_AGENTS / s;
}

extern "C" void kernel_launch(void* const* d_in, const int* in_sizes, int n_in,
                              void* d_out, int out_size, void* d_ws, size_t ws_size,
                              hipStream_t stream) {
    const float* q  = (const float*)d_in[0];   // agents_q  [128,512,11]
    const float* gs = (const float*)d_in[1];   // global_state [128,512,1265]
    float* out = (float*)d_out;                // [128,512,1] f32

    int B = in_sizes[0] / N_AGENTS;            // 65536
    const int block = 256;
    int grid = (B + block - 1) / block;
    qmix_kernel<<<grid, block, 0, stream>>>(q, gs, out, B);
}